// Round 1
// baseline (198.206 us; speedup 1.0000x reference)
//
#include <hip/hip_runtime.h>

#define ED 64
#define HD 4
#define BD 1024
#define SNEG 22222
#define NT 1389              // ceil(SNEG/16)
#define SPAD (NT*16)         // 22224
#define SP1 (SNEG+1)         // 22223, probs row stride
#define LOGQ -3.81776242f    // log(-expm1(S*log1p(-1/V)))

typedef short bf16x8 __attribute__((ext_vector_type(8)));
typedef float f32x4 __attribute__((ext_vector_type(4)));

static __device__ __forceinline__ short f2bf(float f) {
    union { float f; unsigned u; } v; v.f = f;
    return (short)((v.u + 0x7FFFu + ((v.u >> 16) & 1u)) >> 16);
}

// ---------------- kernel 1a: per-batch prep -----------------
// mos_proj (tanh proj) -> A bf16 [B*H][64] (row = b*4+h), pi, true_logit
__global__ __launch_bounds__(256) void k_prep(
        const float* __restrict__ inputs, const float* __restrict__ emb,
        const float* __restrict__ proj,   const float* __restrict__ mix,
        const float* __restrict__ biases, const int* __restrict__ label,
        short* __restrict__ A, float* __restrict__ pi, float* __restrict__ tl) {
    int b = blockIdx.x, t = threadIdx.x;
    __shared__ float s_in[64];
    __shared__ float s_proj[256];
    __shared__ float s_mix[4];
    __shared__ float s_red[256];
    if (t < 64) s_in[t] = inputs[b*64 + t];
    __syncthreads();
    // thread t computes mos_proj element (h = t>>6, e = t&63); proj row index == t
    const float* pr = proj + t*64;
    float dot = 0.f;
    #pragma unroll
    for (int k = 0; k < 64; k += 4)
        dot += s_in[k]*pr[k] + s_in[k+1]*pr[k+1] + s_in[k+2]*pr[k+2] + s_in[k+3]*pr[k+3];
    float val = tanhf(dot);
    s_proj[t] = val;
    A[(b*4 + (t >> 6))*64 + (t & 63)] = f2bf(val);
    if (t < 4) {
        const float* mr = mix + t*64;
        float md = 0.f;
        for (int k = 0; k < 64; ++k) md += s_in[k]*mr[k];
        s_mix[t] = md;
    }
    int lab = label[b];
    s_red[t] = s_proj[t] * emb[(size_t)lab*64 + (t & 63)];
    __syncthreads();
    if (t < 4) {
        float m = fmaxf(fmaxf(s_mix[0], s_mix[1]), fmaxf(s_mix[2], s_mix[3]));
        float e0 = __expf(s_mix[0]-m), e1 = __expf(s_mix[1]-m);
        float e2 = __expf(s_mix[2]-m), e3 = __expf(s_mix[3]-m);
        pi[b*4 + t] = __expf(s_mix[t]-m) / (e0+e1+e2+e3);
        float sum = 0.f;
        for (int k = 0; k < 64; ++k) sum += s_red[t*64 + k];
        tl[b*4 + t] = sum + biases[lab] - LOGQ;   // true logit
    }
}

// ---------------- kernel 1b: gather sampled emb rows -> bf16 W + bias_s ----
__global__ __launch_bounds__(256) void k_gather(
        const float* __restrict__ emb, const float* __restrict__ biases,
        const int* __restrict__ sids, short* __restrict__ W,
        float* __restrict__ bias_s) {
    int t = blockIdx.x*256 + threadIdx.x;
    int s = t >> 3;       // 8 threads per row
    int l8 = t & 7;       // each thread: 8 floats -> 8 bf16
    if (s >= SPAD) return;
    if (s < SNEG) {
        int id = sids[s];
        const float* src = emb + (size_t)id*64 + l8*8;
        bf16x8 o;
        #pragma unroll
        for (int j = 0; j < 8; ++j) o[j] = f2bf(src[j]);
        *(bf16x8*)(W + s*64 + l8*8) = o;
        if (l8 == 0) bias_s[s] = biases[id] - LOGQ;
    } else {
        bf16x8 o;
        #pragma unroll
        for (int j = 0; j < 8; ++j) o[j] = 0;
        *(bf16x8*)(W + s*64 + l8*8) = o;
        if (l8 == 0) bias_s[s] = -1e30f;   // exp -> 0, pad cols contribute nothing
    }
}

// ---------------- kernel 2: denominators via MFMA GEMM (no C store) -------
__global__ __launch_bounds__(256) void k_denom(
        const short* __restrict__ A, const short* __restrict__ W,
        const float* __restrict__ bias_s, float* __restrict__ denom) {
    int tid = threadIdx.x;
    int wave = tid >> 6, lane = tid & 63;
    int g = lane >> 4, c = lane & 15;
    int mbase = blockIdx.y*64 + wave*16;      // global bh-row base of this wave's tile
    const bf16x8* a_ptr = (const bf16x8*)(A + (size_t)(mbase + c)*64);
    bf16x8 a0 = a_ptr[g];                     // k = g*8 .. +7
    bf16x8 a1 = a_ptr[4 + g];                 // k = 32 + g*8 ..
    float s0 = 0.f, s1 = 0.f, s2 = 0.f, s3 = 0.f;
    for (int st = blockIdx.x; st < NT; st += gridDim.x) {
        const bf16x8* b_ptr = (const bf16x8*)(W + (size_t)(st*16 + c)*64);
        bf16x8 b0 = b_ptr[g], b1 = b_ptr[4 + g];
        f32x4 cc = {0.f, 0.f, 0.f, 0.f};
        cc = __builtin_amdgcn_mfma_f32_16x16x32_bf16(a0, b0, cc, 0, 0, 0);
        cc = __builtin_amdgcn_mfma_f32_16x16x32_bf16(a1, b1, cc, 0, 0, 0);
        float bias = bias_s[st*16 + c];       // this lane's column
        s0 += __expf(cc[0] + bias);
        s1 += __expf(cc[1] + bias);
        s2 += __expf(cc[2] + bias);
        s3 += __expf(cc[3] + bias);
    }
    #pragma unroll
    for (int m = 1; m < 16; m <<= 1) {        // reduce over the 16 columns
        s0 += __shfl_xor(s0, m);
        s1 += __shfl_xor(s1, m);
        s2 += __shfl_xor(s2, m);
        s3 += __shfl_xor(s3, m);
    }
    if (c == 0) {                             // rows mbase+g*4+r, r=0..3
        atomicAdd(&denom[mbase + g*4 + 0], s0);
        atomicAdd(&denom[mbase + g*4 + 1], s1);
        atomicAdd(&denom[mbase + g*4 + 2], s2);
        atomicAdd(&denom[mbase + g*4 + 3], s3);
    }
}

// ---------------- kernel 2b: coeff = pi/denom, probs[:,0], loss -----------
__global__ __launch_bounds__(1024) void k_coeff(
        const float* __restrict__ pi, const float* __restrict__ tl,
        const float* __restrict__ denom, float* __restrict__ coeff,
        float* __restrict__ out) {
    int b = threadIdx.x;
    __shared__ float s_red[1024];
    float p0 = 0.f;
    #pragma unroll
    for (int h = 0; h < 4; ++h) {
        float t  = tl[b*4 + h];
        float et = __expf(t);
        float d  = denom[b*4 + h] + et;       // full softmax denominator
        float cf = pi[b*4 + h] / d;
        coeff[b*4 + h] = cf;
        p0 += cf * et;
    }
    out[(size_t)b * SP1] = p0;
    s_red[b] = logf(p0);
    __syncthreads();
    for (int off = 512; off > 0; off >>= 1) {
        if (b < off) s_red[b] += s_red[b + off];
        __syncthreads();
    }
    if (b == 0) out[(size_t)BD * SP1] = -s_red[0] / (float)BD;
}

// ---------------- kernel 3: probs via second MFMA GEMM pass ---------------
__global__ __launch_bounds__(256) void k_probs(
        const short* __restrict__ A, const short* __restrict__ W,
        const float* __restrict__ bias_s, const float* __restrict__ coeff,
        float* __restrict__ out) {
    int tid = threadIdx.x;
    int wave = tid >> 6, lane = tid & 63;
    int g = lane >> 4, c = lane & 15;
    int mbase = blockIdx.y*64 + wave*16;
    const bf16x8* a_ptr = (const bf16x8*)(A + (size_t)(mbase + c)*64);
    bf16x8 a0 = a_ptr[g];
    bf16x8 a1 = a_ptr[4 + g];
    // this lane's 4 accumulator rows are the 4 heads of batch row b:
    int b = (mbase >> 2) + g;
    float cf0 = coeff[mbase + g*4 + 0];
    float cf1 = coeff[mbase + g*4 + 1];
    float cf2 = coeff[mbase + g*4 + 2];
    float cf3 = coeff[mbase + g*4 + 3];
    float* orow = out + (size_t)b * SP1 + 1;
    for (int st = blockIdx.x; st < NT; st += gridDim.x) {
        const bf16x8* b_ptr = (const bf16x8*)(W + (size_t)(st*16 + c)*64);
        bf16x8 b0 = b_ptr[g], b1 = b_ptr[4 + g];
        f32x4 cc = {0.f, 0.f, 0.f, 0.f};
        cc = __builtin_amdgcn_mfma_f32_16x16x32_bf16(a0, b0, cc, 0, 0, 0);
        cc = __builtin_amdgcn_mfma_f32_16x16x32_bf16(a1, b1, cc, 0, 0, 0);
        int scol = st*16 + c;
        float bias = bias_s[scol];
        float p = cf0*__expf(cc[0] + bias) + cf1*__expf(cc[1] + bias)
                + cf2*__expf(cc[2] + bias) + cf3*__expf(cc[3] + bias);
        if (scol < SNEG) orow[scol] = p;
    }
}

extern "C" void kernel_launch(void* const* d_in, const int* in_sizes, int n_in,
                              void* d_out, int out_size, void* d_ws, size_t ws_size,
                              hipStream_t stream) {
    const float* inputs = (const float*)d_in[0];
    const float* emb    = (const float*)d_in[1];
    const float* proj   = (const float*)d_in[2];
    const float* mix    = (const float*)d_in[3];
    const float* biases = (const float*)d_in[4];
    const int*   label  = (const int*)d_in[5];
    const int*   sids   = (const int*)d_in[6];
    float* out = (float*)d_out;

    char* ws = (char*)d_ws;
    short* W      = (short*)(ws);                               // SPAD*64*2 = 2,844,672 B
    short* A      = (short*)(ws + 2844672);                     // 4096*64*2 = 524,288 B
    float* bias_s = (float*)(ws + 2844672 + 524288);            // SPAD*4    = 88,896 B
    float* pi     = (float*)(ws + 2844672 + 524288 + 88896);    // 16 KB
    float* tl     = (float*)(ws + 2844672 + 524288 + 88896 + 16384);
    float* denom  = (float*)(ws + 2844672 + 524288 + 88896 + 32768);
    float* coeff  = (float*)(ws + 2844672 + 524288 + 88896 + 49152);

    k_prep<<<BD, 256, 0, stream>>>(inputs, emb, proj, mix, biases, label, A, pi, tl);
    k_gather<<<(SPAD*8 + 255)/256, 256, 0, stream>>>(emb, biases, sids, W, bias_s);
    hipMemsetAsync(denom, 0, BD*HD*sizeof(float), stream);
    k_denom<<<dim3(32, 64), 256, 0, stream>>>(A, W, bias_s, denom);
    k_coeff<<<1, 1024, 0, stream>>>(pi, tl, denom, coeff, out);
    k_probs<<<dim3(32, 64), 256, 0, stream>>>(A, W, bias_s, coeff, out);
}

// Round 2
// 195.396 us; speedup vs baseline: 1.0144x; 1.0144x over previous
//
#include <hip/hip_runtime.h>

#define ED 64
#define HD 4
#define BD 1024
#define SNEG 22222
#define NT 1389              // ceil(SNEG/16)
#define SPAD (NT*16)         // 22224
#define SP1 (SNEG+1)         // 22223, probs row stride
#define LOGQ -3.81776242f    // log(-expm1(S*log1p(-1/V)))
#define NXB 32               // column-split blocks
#define CPB ((NT + NXB - 1)/NXB)   // 44 contiguous tiles per block

typedef short bf16x8 __attribute__((ext_vector_type(8)));
typedef float f32x4 __attribute__((ext_vector_type(4)));

static __device__ __forceinline__ short f2bf(float f) {
    union { float f; unsigned u; } v; v.f = f;
    return (short)((v.u + 0x7FFFu + ((v.u >> 16) & 1u)) >> 16);
}

static __device__ __forceinline__ float fast_tanh(float x) {
    float ax = __builtin_fabsf(x);
    float e  = __expf(-2.f * ax);          // e^(−2|x|)
    float t  = (1.f - e) / (1.f + e);      // tanh(|x|)
    return __builtin_copysignf(t, x);
}

// ---------------- kernel A: fused setup --------------------------------
// blocks [0,1024): per-batch prep -> A bf16, pi, true_logit
// blocks [1024,1024+695): gather sampled emb -> W bf16, bias_s; zero denom/loss
__global__ __launch_bounds__(256) void k_setup(
        const float* __restrict__ inputs, const float* __restrict__ emb,
        const float* __restrict__ proj,   const float* __restrict__ mix,
        const float* __restrict__ biases, const int* __restrict__ label,
        const int* __restrict__ sids,
        short* __restrict__ A, float* __restrict__ pi, float* __restrict__ tl,
        short* __restrict__ W, float* __restrict__ bias_s,
        float* __restrict__ denom, float* __restrict__ ws_loss) {
    if (blockIdx.x < BD) {
        int b = blockIdx.x, t = threadIdx.x;
        __shared__ float s_in[64];
        __shared__ float s_proj[256];
        __shared__ float s_mix[4];
        __shared__ float s_red[256];
        if (t < 64) s_in[t] = inputs[b*64 + t];
        __syncthreads();
        const float* pr = proj + t*64;
        float dot = 0.f;
        #pragma unroll
        for (int k = 0; k < 64; k += 4)
            dot += s_in[k]*pr[k] + s_in[k+1]*pr[k+1] + s_in[k+2]*pr[k+2] + s_in[k+3]*pr[k+3];
        float val = fast_tanh(dot);
        s_proj[t] = val;
        A[(b*4 + (t >> 6))*64 + (t & 63)] = f2bf(val);
        if (t < 4) {
            const float* mr = mix + t*64;
            float md = 0.f;
            for (int k = 0; k < 64; ++k) md += s_in[k]*mr[k];
            s_mix[t] = md;
        }
        int lab = label[b];
        s_red[t] = s_proj[t] * emb[(size_t)lab*64 + (t & 63)];
        __syncthreads();
        if (t < 4) {
            float m = fmaxf(fmaxf(s_mix[0], s_mix[1]), fmaxf(s_mix[2], s_mix[3]));
            float e0 = __expf(s_mix[0]-m), e1 = __expf(s_mix[1]-m);
            float e2 = __expf(s_mix[2]-m), e3 = __expf(s_mix[3]-m);
            pi[b*4 + t] = __expf(s_mix[t]-m) / (e0+e1+e2+e3);
            float sum = 0.f;
            for (int k = 0; k < 64; ++k) sum += s_red[t*64 + k];
            tl[b*4 + t] = sum + biases[lab] - LOGQ;
        }
    } else {
        int t = (blockIdx.x - BD)*256 + threadIdx.x;
        if (t < BD*HD) denom[t] = 0.f;
        if (t == BD*HD) *ws_loss = 0.f;
        int s = t >> 3, l8 = t & 7;
        if (s >= SPAD) return;
        if (s < SNEG) {
            int id = sids[s];
            const float* src = emb + (size_t)id*64 + l8*8;
            bf16x8 o;
            #pragma unroll
            for (int j = 0; j < 8; ++j) o[j] = f2bf(src[j]);
            *(bf16x8*)(W + s*64 + l8*8) = o;
            if (l8 == 0) bias_s[s] = biases[id] - LOGQ;
        } else {
            bf16x8 o;
            #pragma unroll
            for (int j = 0; j < 8; ++j) o[j] = 0;
            *(bf16x8*)(W + s*64 + l8*8) = o;
            if (l8 == 0) bias_s[s] = -1e30f;
        }
    }
}

// ---------------- kernel B: denominators (contiguous column ranges) -----
__global__ __launch_bounds__(256) void k_denom(
        const short* __restrict__ A, const short* __restrict__ W,
        const float* __restrict__ bias_s, float* __restrict__ denom) {
    int tid = threadIdx.x;
    int wave = tid >> 6, lane = tid & 63;
    int g = lane >> 4, c = lane & 15;
    int mbase = blockIdx.y*64 + wave*16;
    const bf16x8* a_ptr = (const bf16x8*)(A + (size_t)(mbase + c)*64);
    bf16x8 a0 = a_ptr[g];
    bf16x8 a1 = a_ptr[4 + g];
    int st0 = blockIdx.x * CPB;
    int st1 = st0 + CPB; if (st1 > NT) st1 = NT;
    float s0 = 0.f, s1 = 0.f, s2 = 0.f, s3 = 0.f;
    for (int st = st0; st < st1; ++st) {
        const bf16x8* b_ptr = (const bf16x8*)(W + (size_t)(st*16 + c)*64);
        bf16x8 b0 = b_ptr[g], b1 = b_ptr[4 + g];
        f32x4 cc = {0.f, 0.f, 0.f, 0.f};
        cc = __builtin_amdgcn_mfma_f32_16x16x32_bf16(a0, b0, cc, 0, 0, 0);
        cc = __builtin_amdgcn_mfma_f32_16x16x32_bf16(a1, b1, cc, 0, 0, 0);
        float bias = bias_s[st*16 + c];
        s0 += __expf(cc[0] + bias);
        s1 += __expf(cc[1] + bias);
        s2 += __expf(cc[2] + bias);
        s3 += __expf(cc[3] + bias);
    }
    #pragma unroll
    for (int m = 1; m < 16; m <<= 1) {
        s0 += __shfl_xor(s0, m);
        s1 += __shfl_xor(s1, m);
        s2 += __shfl_xor(s2, m);
        s3 += __shfl_xor(s3, m);
    }
    if (c == 0) {
        atomicAdd(&denom[mbase + g*4 + 0], s0);
        atomicAdd(&denom[mbase + g*4 + 1], s1);
        atomicAdd(&denom[mbase + g*4 + 2], s2);
        atomicAdd(&denom[mbase + g*4 + 3], s3);
    }
}

// ---------------- kernel C: coeff = pi/denom, probs[:,0], loss partials --
__global__ __launch_bounds__(256) void k_coeff(
        const float* __restrict__ pi, const float* __restrict__ tl,
        const float* __restrict__ denom, float* __restrict__ coeff,
        float* __restrict__ out, float* __restrict__ ws_loss) {
    int b = blockIdx.x*256 + threadIdx.x;
    float p0 = 0.f;
    #pragma unroll
    for (int h = 0; h < 4; ++h) {
        float t  = tl[b*4 + h];
        float et = __expf(t);
        float d  = denom[b*4 + h] + et;
        float cf = pi[b*4 + h] / d;
        coeff[b*4 + h] = cf;
        p0 += cf * et;
    }
    out[(size_t)b * SP1] = p0;
    float lg = logf(p0);
    #pragma unroll
    for (int m = 1; m < 64; m <<= 1) lg += __shfl_xor(lg, m);
    if ((threadIdx.x & 63) == 0) atomicAdd(ws_loss, lg);
}

// ---------------- kernel D: probs (contiguous column ranges) + loss ------
__global__ __launch_bounds__(256) void k_probs(
        const short* __restrict__ A, const short* __restrict__ W,
        const float* __restrict__ bias_s, const float* __restrict__ coeff,
        const float* __restrict__ ws_loss, float* __restrict__ out) {
    if (blockIdx.x == 0 && blockIdx.y == 0 && threadIdx.x == 0)
        out[(size_t)BD * SP1] = -(*ws_loss) * (1.f / (float)BD);
    int tid = threadIdx.x;
    int wave = tid >> 6, lane = tid & 63;
    int g = lane >> 4, c = lane & 15;
    int mbase = blockIdx.y*64 + wave*16;
    const bf16x8* a_ptr = (const bf16x8*)(A + (size_t)(mbase + c)*64);
    bf16x8 a0 = a_ptr[g];
    bf16x8 a1 = a_ptr[4 + g];
    int b = (mbase >> 2) + g;
    float cf0 = coeff[mbase + g*4 + 0];
    float cf1 = coeff[mbase + g*4 + 1];
    float cf2 = coeff[mbase + g*4 + 2];
    float cf3 = coeff[mbase + g*4 + 3];
    float* orow = out + (size_t)b * SP1 + 1;
    int st0 = blockIdx.x * CPB;
    int st1 = st0 + CPB; if (st1 > NT) st1 = NT;
    for (int st = st0; st < st1; ++st) {
        const bf16x8* b_ptr = (const bf16x8*)(W + (size_t)(st*16 + c)*64);
        bf16x8 b0 = b_ptr[g], b1 = b_ptr[4 + g];
        f32x4 cc = {0.f, 0.f, 0.f, 0.f};
        cc = __builtin_amdgcn_mfma_f32_16x16x32_bf16(a0, b0, cc, 0, 0, 0);
        cc = __builtin_amdgcn_mfma_f32_16x16x32_bf16(a1, b1, cc, 0, 0, 0);
        int scol = st*16 + c;
        float bias = bias_s[scol];
        float p = cf0*__expf(cc[0] + bias) + cf1*__expf(cc[1] + bias)
                + cf2*__expf(cc[2] + bias) + cf3*__expf(cc[3] + bias);
        if (scol < SNEG) orow[scol] = p;
    }
}

extern "C" void kernel_launch(void* const* d_in, const int* in_sizes, int n_in,
                              void* d_out, int out_size, void* d_ws, size_t ws_size,
                              hipStream_t stream) {
    const float* inputs = (const float*)d_in[0];
    const float* emb    = (const float*)d_in[1];
    const float* proj   = (const float*)d_in[2];
    const float* mix    = (const float*)d_in[3];
    const float* biases = (const float*)d_in[4];
    const int*   label  = (const int*)d_in[5];
    const int*   sids   = (const int*)d_in[6];
    float* out = (float*)d_out;

    char* ws = (char*)d_ws;
    short* W       = (short*)(ws);                               // 2,844,672 B
    short* A       = (short*)(ws + 2844672);                     // 524,288 B
    float* bias_s  = (float*)(ws + 2844672 + 524288);            // 88,896 B
    float* pi      = (float*)(ws + 2844672 + 524288 + 88896);
    float* tl      = (float*)(ws + 2844672 + 524288 + 88896 + 16384);
    float* denom   = (float*)(ws + 2844672 + 524288 + 88896 + 32768);
    float* coeff   = (float*)(ws + 2844672 + 524288 + 88896 + 49152);
    float* ws_loss = (float*)(ws + 2844672 + 524288 + 88896 + 65536);

    int gather_blocks = (SPAD*8 + 255)/256;                      // 695
    k_setup<<<BD + gather_blocks, 256, 0, stream>>>(
        inputs, emb, proj, mix, biases, label, sids,
        A, pi, tl, W, bias_s, denom, ws_loss);
    k_denom<<<dim3(NXB, 64), 256, 0, stream>>>(A, W, bias_s, denom);
    k_coeff<<<BD/256, 256, 0, stream>>>(pi, tl, denom, coeff, out, ws_loss);
    k_probs<<<dim3(NXB, 64), 256, 0, stream>>>(A, W, bias_s, coeff, ws_loss, out);
}